// Round 1
// baseline (112.936 us; speedup 1.0000x reference)
//
#include <hip/hip_runtime.h>
#include <math.h>

#define BS    128
#define NC    1024
#define UNITS 512
#define FEAT  512
#define FOURU 2048

typedef short bf16x8 __attribute__((ext_vector_type(8)));
typedef float f32x4  __attribute__((ext_vector_type(4)));

// round-half-up bf16: |err| <= 0.5 ulp (same bound as RNE), 2 VALU ops
__device__ __forceinline__ unsigned short bf_rhu(float f) {
    union { float f; unsigned u; } v; v.f = f;
    return (unsigned short)((v.u + 0x8000u) >> 16);
}

// ---- K1: fused argmax + both GEMM halves --------------------------------
// grid 512 x 256 threads, one block per CU-slot x2.
//   bid <  256 : x-part  : z[0][b][n] = sum_k x[b][k]                 * kern[k][n]
//   bid >= 256 : rec-part: z[1][b][n] = sum_k h_states[argmax(b)][k] * reck[k][n]
// rec blocks recompute the argmax for the 64 rows they own (L2-hot logits,
// deterministic lowest-index tie-break -> identical result in every block).
// nt==0 rec blocks also publish sidx for the scatter kernel.
__global__ __launch_bounds__(256) void gemm_fused_kernel(
    const float* __restrict__ logits,
    const float* __restrict__ x,
    const float* __restrict__ h_states,
    const float* __restrict__ kern,
    const float* __restrict__ reck,
    int*   __restrict__ sidx,
    float* __restrict__ z)            // [2][128][2048] f32
{
    const int t    = threadIdx.x;
    const int wid  = t >> 6, lane = t & 63, l15 = lane & 15, quad = lane >> 4;
    const int bid  = blockIdx.x;
    const bool isrec = bid >= 256;
    const int lb   = isrec ? bid - 256 : bid;
    const int nt   = lb >> 1, mh = lb & 1;
    const int n    = nt * 16 + l15;        // output column
    const int mbase = mh * 64;             // first of this block's 64 rows

    __shared__ int smax[64];

    if (isrec) {
        // ---- phase A: argmax over logits rows [mbase, mbase+64) ----
        // 4 threads per row, 256 elems each, float4 loads; strict '>' keeps
        // the lowest index on ties (matches previous kernel's semantics).
        int r = mbase + (t >> 2);
        int q = t & 3;
        const float* lp = logits + (long)r * NC + q * 256;
        float best = -INFINITY; int bi = 0;
        #pragma unroll 4
        for (int i = 0; i < 256; i += 4) {
            float4 v = *(const float4*)(lp + i);
            int base = q * 256 + i;
            if (v.x > best) { best = v.x; bi = base; }
            if (v.y > best) { best = v.y; bi = base + 1; }
            if (v.z > best) { best = v.z; bi = base + 2; }
            if (v.w > best) { best = v.w; bi = base + 3; }
        }
        #pragma unroll
        for (int m = 1; m <= 2; m <<= 1) {
            float ov = __shfl_xor(best, m);
            int   oi = __shfl_xor(bi, m);
            if (ov > best || (ov == best && oi < bi)) { best = ov; bi = oi; }
        }
        if (q == 0) smax[t >> 2] = bi;
        __syncthreads();
        if (nt == 0 && t < 64) sidx[mbase + t] = smax[t];
    }

    // ---- phase B: gemm, 16 ksteps of 16x16x32 bf16 MFMA ----
    const float* W = isrec ? reck : kern;
    const float* A;
    long abase;
    if (isrec) {
        A = h_states;
        abase = (long)smax[wid * 16 + l15] * UNITS;   // gathered h0 row
    } else {
        A = x;
        abase = (long)(mbase + wid * 16 + l15) * FEAT;
    }

    f32x4 acc = {0.f, 0.f, 0.f, 0.f};
    #pragma unroll
    for (int kstep = 0; kstep < 16; ++kstep) {
        int k0 = kstep * 32 + quad * 8;
        float4 a0 = *(const float4*)(A + abase + k0);
        float4 a1 = *(const float4*)(A + abase + k0 + 4);
        bf16x8 af;
        af[0] = (short)bf_rhu(a0.x); af[1] = (short)bf_rhu(a0.y);
        af[2] = (short)bf_rhu(a0.z); af[3] = (short)bf_rhu(a0.w);
        af[4] = (short)bf_rhu(a1.x); af[5] = (short)bf_rhu(a1.y);
        af[6] = (short)bf_rhu(a1.z); af[7] = (short)bf_rhu(a1.w);

        const float* Wp = W + (long)k0 * FOURU + n;
        bf16x8 wf;
        #pragma unroll
        for (int j = 0; j < 8; ++j)
            wf[j] = (short)bf_rhu(Wp[(long)j * FOURU]);

        acc = __builtin_amdgcn_mfma_f32_16x16x32_bf16(af, wf, acc, 0, 0, 0);
    }

    // C/D layout: col = lane&15, row = quad*4 + reg
    float* zp = z + (isrec ? (long)BS * FOURU : 0);
    #pragma unroll
    for (int r2 = 0; r2 < 4; ++r2) {
        int m = mbase + wid * 16 + quad * 4 + r2;
        zp[(long)m * FOURU + n] = acc[r2];
    }
}

// ---- K2: fused LSTM + diff_scatter (2 z slices) -------------------------
// one block per class row j, 512 threads = one unit each.
__global__ __launch_bounds__(512) void scatter_lstm_kernel(
    const float* __restrict__ z, const float* __restrict__ bias,
    const float* __restrict__ h_states, const float* __restrict__ c_states,
    const int* __restrict__ sidx,
    float* __restrict__ h_out, float* __restrict__ out_h, float* __restrict__ out_c)
{
    __shared__ int s[BS];
    int t = threadIdx.x;
    if (t < BS) s[t] = sidx[t];
    __syncthreads();
    int j = blockIdx.x;
    int u = t;

    float ah = h_states[(long)j * UNITS + u];
    float ac = c_states[(long)j * UNITS + u];   // == c0 for any matching b

    float mh = -INFINITY, mc = -INFINITY;
    int count = 0;
    float bi_ = bias[u], bf_ = bias[512 + u], bg_ = bias[1024 + u], bo_ = bias[1536 + u];

    for (int b = 0; b < BS; ++b) {
        if (s[b] == j) {                          // block-uniform branch
            ++count;
            const float* z0 = z + (long)b * FOURU;
            const float* z1 = z + (long)BS * FOURU + (long)b * FOURU;
            float zi = bi_ + z0[u]        + z1[u];
            float zf = bf_ + z0[512 + u]  + z1[512 + u];
            float zg = bg_ + z0[1024 + u] + z1[1024 + u];
            float zo = bo_ + z0[1536 + u] + z1[1536 + u];
            float ig = 1.f / (1.f + expf(-zi));
            float fg = 1.f / (1.f + expf(-zf));
            float gg = tanhf(zg);
            float og = 1.f / (1.f + expf(-zo));
            float c  = fg * ac + ig * gg;
            float h  = og * tanhf(c);
            h_out[(long)b * UNITS + u] = h;
            mh = fmaxf(mh, h);
            mc = fmaxf(mc, c);
        }
    }
    // count==BS: old state never appears in the blend; count==0 -> old state
    out_h[(long)j * UNITS + u] = (count == BS) ? mh : fmaxf(ah, mh);
    out_c[(long)j * UNITS + u] = (count == BS) ? mc : fmaxf(ac, mc);
}

extern "C" void kernel_launch(void* const* d_in, const int* in_sizes, int n_in,
                              void* d_out, int out_size, void* d_ws, size_t ws_size,
                              hipStream_t stream)
{
    (void)in_sizes; (void)n_in; (void)out_size; (void)ws_size;
    const float* x      = (const float*)d_in[0];
    const float* logits = (const float*)d_in[1];
    const float* h_st   = (const float*)d_in[2];
    const float* c_st   = (const float*)d_in[3];
    const float* kern   = (const float*)d_in[4];
    const float* reck   = (const float*)d_in[5];
    const float* bias   = (const float*)d_in[6];

    float* out        = (float*)d_out;
    float* out_h_step = out;                          // (128,512)
    float* out_newh   = out + BS * UNITS;             // (1024,512)
    float* out_newc   = out + BS * UNITS + NC * UNITS;

    char* ws   = (char*)d_ws;
    int*  sidx = (int*)ws;                            // 512 B
    float* z   = (float*)(ws + 4096);                 // 2 MB: [2][128][2048]

    gemm_fused_kernel<<<512, 256, 0, stream>>>(logits, x, h_st, kern, reck, sidx, z);
    scatter_lstm_kernel<<<NC, 512, 0, stream>>>(
        z, bias, h_st, c_st, sidx, out_h_step, out_newh, out_newc);
}

// Round 2
// 101.702 us; speedup vs baseline: 1.1105x; 1.1105x over previous
//
#include <hip/hip_runtime.h>
#include <math.h>

#define BS    128
#define NC    1024
#define UNITS 512
#define FEAT  512
#define FOURU 2048
#define KG    4          // k-groups (1024/4 = 256 per group)

typedef short bf16x8 __attribute__((ext_vector_type(8)));
typedef float f32x4  __attribute__((ext_vector_type(4)));

// round-half-up bf16: |err| <= 0.5 ulp (same bound as RNE), 2 VALU ops
__device__ __forceinline__ unsigned short bf_rhu(float f) {
    union { float f; unsigned u; } v; v.f = f;
    return (unsigned short)((v.u + 0x8000u) >> 16);
}
__device__ __forceinline__ unsigned pack2(float a, float b) {
    return (unsigned)bf_rhu(a) | ((unsigned)bf_rhu(b) << 16);
}

// ---- K1: per-row argmax + build A_bf16 = [x | h_states[argmax]] ---------
__global__ __launch_bounds__(256) void argmax_prep_kernel(
    const float* __restrict__ logits, const float* __restrict__ x,
    const float* __restrict__ h_states,
    int* __restrict__ sidx, unsigned* __restrict__ Abf /* uint view, 512/row */)
{
    int b = blockIdx.x;
    int t = threadIdx.x;
    float best = -INFINITY; int bi = 0;
    for (int i = t; i < NC; i += 256) {
        float v = logits[b * NC + i];
        if (v > best) { best = v; bi = i; }
    }
    for (int off = 32; off > 0; off >>= 1) {
        float ov = __shfl_down(best, off);
        int   oi = __shfl_down(bi, off);
        if (ov > best || (ov == best && oi < bi)) { best = ov; bi = oi; }
    }
    __shared__ float sv[4]; __shared__ int si[4]; __shared__ int sbi;
    int wid = t >> 6;
    if ((t & 63) == 0) { sv[wid] = best; si[wid] = bi; }
    __syncthreads();
    if (t == 0) {
        for (int w = 1; w < 4; ++w)
            if (sv[w] > best || (sv[w] == best && si[w] < bi)) { best = sv[w]; bi = si[w]; }
        sidx[b] = bi;
        sbi = bi;
    }
    __syncthreads();
    int st = t & 127;
    const float* srcrow = (t < 128) ? (x + (long)b * FEAT)
                                    : (h_states + (long)sbi * UNITS);
    float4 v = *(const float4*)(srcrow + st * 4);
    unsigned lo = pack2(v.x, v.y), hi = pack2(v.z, v.w);
    unsigned du = (unsigned)b * 512u + (t < 128 ? 0u : 256u) + (unsigned)st * 2u;
    *(uint2*)(Abf + du) = make_uint2(lo, hi);
}

// ---- K2: z_part[kg] = A[:, ks] @ W[ks, :] -- zero LDS, zero barriers ----
// grid (32 nt, 4 kg, 4 mz) = 512 blocks. Each block: 32 rows x 64 cols x
// 256 K. The 4 waves cover 4 ADJACENT 16-col n-tiles, so their 64 B W
// row-segments tile full 256 B line groups -> every fetched L2 line is
// fully consumed (round-0's 16-col blocks wasted half of every 128 B line
// and each wave redundantly loaded identical W fragments).
// A fragments (bf16, 16-B loads) are shared across waves -> L1-hot.
__global__ __launch_bounds__(256) void gemm_kernel(
    const unsigned short* __restrict__ Abf,   // [128][1024] bf16
    const float* __restrict__ kern, const float* __restrict__ reck,
    float* __restrict__ z_part)               // [KG][128][2048] f32
{
    const int t = threadIdx.x;
    const int wid = t >> 6, lane = t & 63, l15 = lane & 15, quad = lane >> 4;
    const int nt = blockIdx.x, kg = blockIdx.y, mz = blockIdx.z;
    const int n  = nt * 64 + wid * 16 + l15;           // output column
    const int k0base = kg * 256;                       // k offset inside A
    const float* W  = (kg < 2) ? kern : reck;
    const int wkbase = (kg & 1) * 256;                 // k offset inside W matrix

    f32x4 zero = {0.f, 0.f, 0.f, 0.f};
    f32x4 acc[2] = {zero, zero};

    #pragma unroll
    for (int kstep = 0; kstep < 8; ++kstep) {
        int k0  = k0base + kstep * 32 + quad * 8;
        int wk0 = wkbase + kstep * 32 + quad * 8;

        bf16x8 af[2], wf;
        #pragma unroll
        for (int ms = 0; ms < 2; ++ms) {
            int m = mz * 32 + ms * 16 + l15;
            af[ms] = *(const bf16x8*)(Abf + (long)m * 1024 + k0);
        }
        const float* Wp = W + (long)wk0 * FOURU + n;
        #pragma unroll
        for (int j = 0; j < 8; ++j)
            wf[j] = (short)bf_rhu(Wp[(long)j * FOURU]);

        #pragma unroll
        for (int ms = 0; ms < 2; ++ms)
            acc[ms] = __builtin_amdgcn_mfma_f32_16x16x32_bf16(af[ms], wf, acc[ms], 0, 0, 0);
    }

    // C/D layout: col = lane&15, row = quad*4 + reg
    float* zp = z_part + (long)kg * BS * FOURU;
    #pragma unroll
    for (int ms = 0; ms < 2; ++ms)
        #pragma unroll
        for (int r = 0; r < 4; ++r) {
            int m = mz * 32 + ms * 16 + quad * 4 + r;
            zp[(long)m * FOURU + n] = acc[ms][r];
        }
}

// ---- K3: fused LSTM + diff_scatter (KG=4) -------------------------------
__global__ __launch_bounds__(256) void scatter_lstm_kernel(
    const float* __restrict__ z_part, const float* __restrict__ bias,
    const float* __restrict__ h_states, const float* __restrict__ c_states,
    const int* __restrict__ sidx,
    float* __restrict__ h_out, float* __restrict__ out_h, float* __restrict__ out_c)
{
    __shared__ int s[BS];
    int t = threadIdx.x;
    if (t < BS) s[t] = sidx[t];
    __syncthreads();
    int j = blockIdx.x >> 1;
    int u = (blockIdx.x & 1) * 256 + t;

    float ah = h_states[(long)j * UNITS + u];
    float ac = c_states[(long)j * UNITS + u];   // == c0 for any matching b

    float mh = -INFINITY, mc = -INFINITY;
    int count = 0;
    float bi_ = bias[u], bf_ = bias[512 + u], bg_ = bias[1024 + u], bo_ = bias[1536 + u];

    for (int b = 0; b < BS; ++b) {
        if (s[b] == j) {                          // block-uniform branch
            ++count;
            float zi = bi_, zf = bf_, zg = bg_, zo = bo_;
            #pragma unroll
            for (int kg = 0; kg < KG; ++kg) {
                const float* zp = z_part + (long)kg * BS * FOURU + (long)b * FOURU;
                zi += zp[u];
                zf += zp[512 + u];
                zg += zp[1024 + u];
                zo += zp[1536 + u];
            }
            float ig = 1.f / (1.f + expf(-zi));
            float fg = 1.f / (1.f + expf(-zf));
            float gg = tanhf(zg);
            float og = 1.f / (1.f + expf(-zo));
            float c  = fg * ac + ig * gg;
            float h  = og * tanhf(c);
            h_out[(long)b * UNITS + u] = h;
            mh = fmaxf(mh, h);
            mc = fmaxf(mc, c);
        }
    }
    // count==BS: old state never appears in the blend; count==0 -> old state
    out_h[(long)j * UNITS + u] = (count == BS) ? mh : fmaxf(ah, mh);
    out_c[(long)j * UNITS + u] = (count == BS) ? mc : fmaxf(ac, mc);
}

extern "C" void kernel_launch(void* const* d_in, const int* in_sizes, int n_in,
                              void* d_out, int out_size, void* d_ws, size_t ws_size,
                              hipStream_t stream)
{
    (void)in_sizes; (void)n_in; (void)out_size; (void)ws_size;
    const float* x      = (const float*)d_in[0];
    const float* logits = (const float*)d_in[1];
    const float* h_st   = (const float*)d_in[2];
    const float* c_st   = (const float*)d_in[3];
    const float* kern   = (const float*)d_in[4];
    const float* reck   = (const float*)d_in[5];
    const float* bias   = (const float*)d_in[6];

    float* out        = (float*)d_out;
    float* out_h_step = out;                          // (128,512)
    float* out_newh   = out + BS * UNITS;             // (1024,512)
    float* out_newc   = out + BS * UNITS + NC * UNITS;

    char*           ws     = (char*)d_ws;
    int*            sidx   = (int*)ws;                    // 512 B
    unsigned*       Abf    = (unsigned*)(ws + 4096);      // 256 KB (uint view)
    float*          z_part = (float*)(ws + (1u << 20));   // 4 MB

    argmax_prep_kernel<<<BS, 256, 0, stream>>>(logits, x, h_st, sidx, Abf);
    gemm_kernel<<<dim3(32, KG, 4), 256, 0, stream>>>(
        (const unsigned short*)Abf, kern, reck, z_part);
    scatter_lstm_kernel<<<NC * UNITS / 256, 256, 0, stream>>>(
        z_part, bias, h_st, c_st, sidx, out_h_step, out_newh, out_newc);
}